// Round 5
// baseline (220.799 us; speedup 1.0000x reference)
//
#include <hip/hip_runtime.h>
#include <math.h>

constexpr int B = 16, S = 512, D = 1024, H = 16, DH = 64;
constexpr int BH = B * H;        // 256

typedef short bf16x8 __attribute__((ext_vector_type(8)));
typedef float f32x4  __attribute__((ext_vector_type(4)));

__device__ __forceinline__ unsigned short f2bf(float f) {
    unsigned u = __float_as_uint(f);
    u += 0x7fff + ((u >> 16) & 1);   // RNE
    return (unsigned short)(u >> 16);
}

#define VMC0  asm volatile("s_waitcnt vmcnt(0)" ::: "memory")
#define BARR  __builtin_amdgcn_s_barrier()

// ---------------------------------------------------------------------------
// x fp32 [B*S][D] -> bf16
// ---------------------------------------------------------------------------
__global__ __launch_bounds__(256) void convert_x(
    const float* __restrict__ x, unsigned short* __restrict__ xb)
{
    int i = blockIdx.x * 256 + threadIdx.x;
    float4 v = ((const float4*)x)[i];
    ushort4 o;
    o.x = f2bf(v.x); o.y = f2bf(v.y); o.z = f2bf(v.z); o.w = f2bf(v.w);
    ((ushort4*)xb)[i] = o;
}

// ---------------------------------------------------------------------------
// W [3][H][D][DH] fp32 -> WbT [3][H][DH][D] bf16 == row-major [3072][1024]
// ---------------------------------------------------------------------------
__global__ __launch_bounds__(256) void convert_w(
    const float* __restrict__ Wq, const float* __restrict__ Wk,
    const float* __restrict__ Wv, unsigned short* __restrict__ WbT)
{
    __shared__ float tile[64][65];
    const int d0 = blockIdx.x * 64;
    const int h = blockIdx.y, m = blockIdx.z;
    const float* W = ((m == 0) ? Wq : (m == 1) ? Wk : Wv) + (size_t)h * D * DH;
    const int t = threadIdx.x;
    {
        int e = t & 63, dr = t >> 6;
        #pragma unroll
        for (int i = 0; i < 16; ++i) {
            int d = dr * 16 + i;
            tile[d][e] = W[(size_t)(d0 + d) * DH + e];
        }
    }
    __syncthreads();
    {
        int d = t & 63, er = t >> 6;
        unsigned short* out = WbT + (size_t)(m * H + h) * DH * D;
        #pragma unroll
        for (int i = 0; i < 16; ++i) {
            int e = er * 16 + i;
            out[(size_t)e * D + d0 + d] = f2bf(tile[d][e]);
        }
    }
}

// ---------------------------------------------------------------------------
// Fused QKV projection: C[8192][3072] = xb . WbT^T, 128x128 block tile,
// 4 waves in 2x2, each 64x64 (4x4 MFMA 16x16x32 bf16), BK=64, 32 KB LDS.
// ROUND-0 PROVEN FORM (73.7 us). The 256^2 8-phase port failed twice with
// identical counters (570 TF, MfmaUtil 22) for reasons not visible in the
// available counters — abandoned this session.
// q scaled by (1/sqrt(D))*log2e; v written transposed [bh][DH][S].
// ---------------------------------------------------------------------------
__global__ __launch_bounds__(256) void qkv_gemm(
    const unsigned short* __restrict__ xb,
    const unsigned short* __restrict__ WbT,
    unsigned short* __restrict__ qkvb)
{
    __shared__ unsigned short As[128 * 64];   // 16 KB, swizzled g^(row&7)
    __shared__ unsigned short Bs[128 * 64];   // 16 KB

    const int t = threadIdx.x;
    const int w = t >> 6;
    const int wr = w >> 1, wc = w & 1;
    const int L = t & 63;
    const int lane15 = L & 15;
    const int quad = L >> 4;
    const int lrow8 = L >> 3;
    const int lg = L & 7;

    const int r0 = blockIdx.x * 128;   // global row (b*S+s)
    const int n0 = blockIdx.y * 128;   // global col in [0, 3072)

    f32x4 acc[4][4] = {};

    for (int k0 = 0; k0 < D; k0 += 64) {
        #pragma unroll
        for (int i = 0; i < 4; ++i) {
            int c = w * 4 + i;
            int r = c * 8 + lrow8;
            int gg = lg ^ (r & 7);
            const unsigned short* gp = xb + (size_t)(r0 + r) * D + k0 + gg * 8;
            __builtin_amdgcn_global_load_lds(
                (const __attribute__((address_space(1))) void*)gp,
                (__attribute__((address_space(3))) void*)(As + c * 512),
                16, 0, 0);
            const unsigned short* gq = WbT + (size_t)(n0 + r) * D + k0 + gg * 8;
            __builtin_amdgcn_global_load_lds(
                (const __attribute__((address_space(1))) void*)gq,
                (__attribute__((address_space(3))) void*)(Bs + c * 512),
                16, 0, 0);
        }
        __syncthreads();

        #pragma unroll
        for (int ks = 0; ks < 2; ++ks) {
            int gk = ks * 4 + quad;
            bf16x8 a[4], bb[4];
            #pragma unroll
            for (int rt = 0; rt < 4; ++rt) {
                int ml = wr * 64 + rt * 16 + lane15;
                a[rt] = *(const bf16x8*)(As + ml * 64 + ((gk ^ (ml & 7)) * 8));
            }
            #pragma unroll
            for (int ct = 0; ct < 4; ++ct) {
                int nl = wc * 64 + ct * 16 + lane15;
                bb[ct] = *(const bf16x8*)(Bs + nl * 64 + ((gk ^ (nl & 7)) * 8));
            }
            #pragma unroll
            for (int rt = 0; rt < 4; ++rt)
                #pragma unroll
                for (int ct = 0; ct < 4; ++ct)
                    acc[rt][ct] = __builtin_amdgcn_mfma_f32_16x16x32_bf16(
                        a[rt], bb[ct], acc[rt][ct], 0, 0, 0);
        }
        __syncthreads();
    }

    const int m  = n0 >> 10;                 // uniform per block
    const int h  = ((n0 >> 6) + wc) & 15;    // one head per wave
    const int bb_ = r0 >> 9;                 // batch
    const int s0 = (r0 & 511) + wr * 64;

    if (m == 2) {
        unsigned short* outv = qkvb + ((size_t)(2 * BH) + (bb_ * H + h)) * (size_t)(S * DH);
        #pragma unroll
        for (int rt = 0; rt < 4; ++rt) {
            int srow = s0 + rt * 16 + quad * 4;
            #pragma unroll
            for (int ct = 0; ct < 4; ++ct) {
                int e = ct * 16 + lane15;
                ushort4 pk;
                pk.x = f2bf(acc[rt][ct][0]);
                pk.y = f2bf(acc[rt][ct][1]);
                pk.z = f2bf(acc[rt][ct][2]);
                pk.w = f2bf(acc[rt][ct][3]);
                *(ushort4*)(outv + (size_t)e * S + srow) = pk;
            }
        }
    } else {
        const float sc = (m == 0) ? 0.04508422002778011f : 1.0f; // (1/32)*log2e
        unsigned short* out = qkvb + ((size_t)m * BH + (bb_ * H + h)) * (size_t)(S * DH);
        #pragma unroll
        for (int rt = 0; rt < 4; ++rt) {
            #pragma unroll
            for (int ct = 0; ct < 4; ++ct) {
                int e = ct * 16 + lane15;
                #pragma unroll
                for (int r = 0; r < 4; ++r) {
                    int srow = s0 + rt * 16 + quad * 4 + r;
                    out[(size_t)srow * DH + e] = f2bf(acc[rt][ct][r] * sc);
                }
            }
        }
    }
}

// ---------------------------------------------------------------------------
// Flash attention v2, BARRIER-FREE: K/V fragments loaded DIRECTLY from
// global to registers (no K/V LDS, no staging, no per-iter vmcnt/barrier).
// Rationale: per-bh K/V is 128 KB (L2-resident, reused by 4 q-blocks) —
// LDS staging was pure overhead (Common-mistake #7) and its per-iteration
// vmcnt(0)+barrier drain serialized a wave-serial dependency chain.
// S^T trick retained: S^T = K.Q^T with key rows permuted by
//   g(r) = r[5]*32 | r[3:2]*8 | r[4]*4 | r[1:0]
// now folded directly into each lane's GLOBAL address:
//   row = kt + (lane15>>2)*8 + (lane15&3) + (ct>>1)*32 + (ct&1)*4
// so exp2'd C-registers still pack IN-LANE into the PV B-fragment.
// Q staged through LDS once (gload_lds), then lives in registers.
// Loop has NO stores and NO syncs -> compiler freely pipelines loads
// across iterations (#pragma unroll 2). setprio(1) around MFMA clusters.
// Grid (S/128, B*H), 4 waves; wave owns 32 q-rows. K-tile 64. LDS 16 KB.
// ---------------------------------------------------------------------------
__global__ __launch_bounds__(256) void attn_mfma(
    const unsigned short* __restrict__ qkvb, float* __restrict__ out)
{
    __shared__ unsigned short Qs[128 * 64];        // 16 KB (Q staging only)

    const int t = threadIdx.x;
    const int w = t >> 6;
    const int L = t & 63;
    const int lane15 = L & 15;
    const int quad = L >> 4;
    const int lrow8 = L >> 3;
    const int lg = L & 7;
    const int qr0 = blockIdx.x * 128;
    const int bh = blockIdx.y;
    const int b = bh >> 4, h = bh & 15;

    const unsigned short* qb = qkvb + (size_t)bh * S * DH;
    const unsigned short* kb = qkvb + (size_t)(BH + bh) * S * DH;
    const unsigned short* vt = qkvb + (size_t)(2 * BH + bh) * S * DH; // [64][512]

    // stage Q once: wave w stages rows [w*32, w*32+32)
    #pragma unroll
    for (int i = 0; i < 4; ++i) {
        int base = w * 32 + i * 8;
        int r = base + lrow8;
        int gg = lg ^ (r & 7);
        const unsigned short* gp = qb + (size_t)(qr0 + r) * DH + gg * 8;
        __builtin_amdgcn_global_load_lds(
            (const __attribute__((address_space(1))) void*)gp,
            (__attribute__((address_space(3))) void*)(Qs + base * 64),
            16, 0, 0);
    }
    VMC0;
    BARR;

    // Q fragments: loaded once, live in registers for the whole kernel
    bf16x8 qf[2][2];
    #pragma unroll
    for (int mt = 0; mt < 2; ++mt)
        #pragma unroll
        for (int ks = 0; ks < 2; ++ks) {
            int ml = w * 32 + mt * 16 + lane15;
            int gk = ks * 4 + quad;
            qf[mt][ks] = *(const bf16x8*)(Qs + ml * 64 + ((gk ^ (lane15 & 7)) * 8));
        }

    // per-lane base pointers for direct K/V fragment loads
    //   K row (within tile) for (ct, lane15): g = gl + (ct>>1)*32 + (ct&1)*4
    const int gl = (lane15 >> 2) * 8 + (lane15 & 3);
    const unsigned short* kpl = kb + (size_t)gl * DH + quad * 8;
    const unsigned short* vpl = vt + (size_t)lane15 * S + quad * 8;

    f32x4 o[2][4] = {};                  // rows = dh-slot, col = qrow(lane15)
    float plsum[2] = {0.f, 0.f};

    #pragma unroll 2
    for (int kt = 0; kt < S; kt += 64) {
        // ---- direct global->register fragment loads (no LDS, no sync) ----
        bf16x8 kf[2][4], vf[2][4];
        #pragma unroll
        for (int ks = 0; ks < 2; ++ks)
            #pragma unroll
            for (int ct = 0; ct < 4; ++ct) {
                int krow = kt + (ct >> 1) * 32 + (ct & 1) * 4;     // + gl in kpl
                kf[ks][ct] = *(const bf16x8*)(kpl + (size_t)krow * DH + ks * 32);
                vf[ks][ct] = *(const bf16x8*)(vpl + (size_t)ct * (16 * S) + kt + ks * 32);
            }

        // ---- S^T = K . Q^T : C row = key-slot (quad*4+reg), col = qrow ----
        f32x4 st[2][4] = {};
        __builtin_amdgcn_s_setprio(1);
        #pragma unroll
        for (int ks = 0; ks < 2; ++ks)
            #pragma unroll
            for (int mt = 0; mt < 2; ++mt)
                #pragma unroll
                for (int ct = 0; ct < 4; ++ct)
                    st[mt][ct] = __builtin_amdgcn_mfma_f32_16x16x32_bf16(
                        kf[ks][ct], qf[mt][ks], st[mt][ct], 0, 0, 0);
        __builtin_amdgcn_s_setprio(0);

        // ---- p = exp2(s); cvt_pk into PV B-fragments; row partials ----
        bf16x8 pB[2][2];
        #pragma unroll
        for (int mt = 0; mt < 2; ++mt) {
            float rs = 0.f;
            union { unsigned u[4]; bf16x8 v; } pu[2];
            #pragma unroll
            for (int ct = 0; ct < 4; ++ct) {
                float p0 = exp2f(st[mt][ct][0]);
                float p1 = exp2f(st[mt][ct][1]);
                float p2 = exp2f(st[mt][ct][2]);
                float p3 = exp2f(st[mt][ct][3]);
                rs += (p0 + p1) + (p2 + p3);
                unsigned lo, hi;
                asm("v_cvt_pk_bf16_f32 %0, %1, %2" : "=v"(lo) : "v"(p0), "v"(p1));
                asm("v_cvt_pk_bf16_f32 %0, %1, %2" : "=v"(hi) : "v"(p2), "v"(p3));
                pu[ct >> 1].u[(ct & 1) * 2 + 0] = lo;
                pu[ct >> 1].u[(ct & 1) * 2 + 1] = hi;
            }
            pB[mt][0] = pu[0].v;
            pB[mt][1] = pu[1].v;
            plsum[mt] += rs;
        }

        // ---- O^T += V^T . P^T  (A = V^T rows from registers, B = P) ----
        __builtin_amdgcn_s_setprio(1);
        #pragma unroll
        for (int ks = 0; ks < 2; ++ks)
            #pragma unroll
            for (int mt = 0; mt < 2; ++mt)
                #pragma unroll
                for (int nt = 0; nt < 4; ++nt)
                    o[mt][nt] = __builtin_amdgcn_mfma_f32_16x16x32_bf16(
                        vf[ks][nt], pB[mt][ks], o[mt][nt], 0, 0, 0);
        __builtin_amdgcn_s_setprio(0);
    }

    // epilogue: quad-reduce row sums, normalize, float4 stores (4 consec dh)
    #pragma unroll
    for (int mt = 0; mt < 2; ++mt) {
        float l = plsum[mt];
        l += __shfl_xor(l, 16, 64);
        l += __shfl_xor(l, 32, 64);
        float inv = 1.0f / l;
        int srow = qr0 + w * 32 + mt * 16 + lane15;
        float* op = out + (size_t)(b * S + srow) * D + h * DH;
        #pragma unroll
        for (int nt = 0; nt < 4; ++nt) {
            float4 v;
            v.x = o[mt][nt][0] * inv;
            v.y = o[mt][nt][1] * inv;
            v.z = o[mt][nt][2] * inv;
            v.w = o[mt][nt][3] * inv;
            *(float4*)(op + nt * 16 + quad * 4) = v;
        }
    }
}

extern "C" void kernel_launch(void* const* d_in, const int* in_sizes, int n_in,
                              void* d_out, int out_size, void* d_ws, size_t ws_size,
                              hipStream_t stream) {
    const float* x  = (const float*)d_in[0];
    const float* Wq = (const float*)d_in[1];
    const float* Wk = (const float*)d_in[2];
    const float* Wv = (const float*)d_in[3];
    float* outp = (float*)d_out;

    // workspace: [0, 50331648) qkvb bf16 (q,k row-major; v transposed)
    //            [50331648, 67108864) xb bf16; [67108864, 73400320) WbT bf16
    unsigned short* qkvb = (unsigned short*)d_ws;
    unsigned short* xb   = (unsigned short*)((char*)d_ws + 50331648);
    unsigned short* WbT  = (unsigned short*)((char*)d_ws + 67108864);

    convert_x<<<dim3((B * S * D / 4) / 256), 256, 0, stream>>>(x, xb);
    convert_w<<<dim3(D / 64, H, 3), 256, 0, stream>>>(Wq, Wk, Wv, WbT);
    qkv_gemm<<<dim3(B * S / 128, 3 * H * DH / 128), 256, 0, stream>>>(xb, WbT, qkvb);
    attn_mfma<<<dim3(S / 128, BH), 256, 0, stream>>>(qkvb, outp);
}

// Round 6
// 196.698 us; speedup vs baseline: 1.1225x; 1.1225x over previous
//
#include <hip/hip_runtime.h>
#include <math.h>

constexpr int B = 16, S = 512, D = 1024, H = 16, DH = 64;
constexpr int BH = B * H;        // 256

typedef short bf16x8 __attribute__((ext_vector_type(8)));
typedef float f32x4  __attribute__((ext_vector_type(4)));

__device__ __forceinline__ unsigned short f2bf(float f) {
    unsigned u = __float_as_uint(f);
    u += 0x7fff + ((u >> 16) & 1);   // RNE
    return (unsigned short)(u >> 16);
}

#define VMC0  asm volatile("s_waitcnt vmcnt(0)" ::: "memory")
#define BARR  __builtin_amdgcn_s_barrier()

// ---------------------------------------------------------------------------
// x fp32 [B*S][D] -> bf16
// ---------------------------------------------------------------------------
__global__ __launch_bounds__(256) void convert_x(
    const float* __restrict__ x, unsigned short* __restrict__ xb)
{
    int i = blockIdx.x * 256 + threadIdx.x;
    float4 v = ((const float4*)x)[i];
    ushort4 o;
    o.x = f2bf(v.x); o.y = f2bf(v.y); o.z = f2bf(v.z); o.w = f2bf(v.w);
    ((ushort4*)xb)[i] = o;
}

// ---------------------------------------------------------------------------
// W [3][H][D][DH] fp32 -> WbT [3][H][DH][D] bf16 == row-major [3072][1024]
// ---------------------------------------------------------------------------
__global__ __launch_bounds__(256) void convert_w(
    const float* __restrict__ Wq, const float* __restrict__ Wk,
    const float* __restrict__ Wv, unsigned short* __restrict__ WbT)
{
    __shared__ float tile[64][65];
    const int d0 = blockIdx.x * 64;
    const int h = blockIdx.y, m = blockIdx.z;
    const float* W = ((m == 0) ? Wq : (m == 1) ? Wk : Wv) + (size_t)h * D * DH;
    const int t = threadIdx.x;
    {
        int e = t & 63, dr = t >> 6;
        #pragma unroll
        for (int i = 0; i < 16; ++i) {
            int d = dr * 16 + i;
            tile[d][e] = W[(size_t)(d0 + d) * DH + e];
        }
    }
    __syncthreads();
    {
        int d = t & 63, er = t >> 6;
        unsigned short* out = WbT + (size_t)(m * H + h) * DH * D;
        #pragma unroll
        for (int i = 0; i < 16; ++i) {
            int e = er * 16 + i;
            out[(size_t)e * D + d0 + d] = f2bf(tile[d][e]);
        }
    }
}

// ---------------------------------------------------------------------------
// Fused QKV projection: C[8192][3072] = xb . WbT^T, 128x128 block tile,
// 4 waves in 2x2, each 64x64 (4x4 MFMA 16x16x32 bf16), BK=64, 32 KB LDS.
// ROUND-0 PROVEN FORM (73.7 us, MfmaUtil 28). Do not touch.
// q scaled by (1/sqrt(D))*log2e; v written transposed [bh][DH][S].
// ---------------------------------------------------------------------------
__global__ __launch_bounds__(256) void qkv_gemm(
    const unsigned short* __restrict__ xb,
    const unsigned short* __restrict__ WbT,
    unsigned short* __restrict__ qkvb)
{
    __shared__ unsigned short As[128 * 64];   // 16 KB, swizzled g^(row&7)
    __shared__ unsigned short Bs[128 * 64];   // 16 KB

    const int t = threadIdx.x;
    const int w = t >> 6;
    const int wr = w >> 1, wc = w & 1;
    const int L = t & 63;
    const int lane15 = L & 15;
    const int quad = L >> 4;
    const int lrow8 = L >> 3;
    const int lg = L & 7;

    const int r0 = blockIdx.x * 128;   // global row (b*S+s)
    const int n0 = blockIdx.y * 128;   // global col in [0, 3072)

    f32x4 acc[4][4] = {};

    for (int k0 = 0; k0 < D; k0 += 64) {
        #pragma unroll
        for (int i = 0; i < 4; ++i) {
            int c = w * 4 + i;
            int r = c * 8 + lrow8;
            int gg = lg ^ (r & 7);
            const unsigned short* gp = xb + (size_t)(r0 + r) * D + k0 + gg * 8;
            __builtin_amdgcn_global_load_lds(
                (const __attribute__((address_space(1))) void*)gp,
                (__attribute__((address_space(3))) void*)(As + c * 512),
                16, 0, 0);
            const unsigned short* gq = WbT + (size_t)(n0 + r) * D + k0 + gg * 8;
            __builtin_amdgcn_global_load_lds(
                (const __attribute__((address_space(1))) void*)gq,
                (__attribute__((address_space(3))) void*)(Bs + c * 512),
                16, 0, 0);
        }
        __syncthreads();

        #pragma unroll
        for (int ks = 0; ks < 2; ++ks) {
            int gk = ks * 4 + quad;
            bf16x8 a[4], bb[4];
            #pragma unroll
            for (int rt = 0; rt < 4; ++rt) {
                int ml = wr * 64 + rt * 16 + lane15;
                a[rt] = *(const bf16x8*)(As + ml * 64 + ((gk ^ (ml & 7)) * 8));
            }
            #pragma unroll
            for (int ct = 0; ct < 4; ++ct) {
                int nl = wc * 64 + ct * 16 + lane15;
                bb[ct] = *(const bf16x8*)(Bs + nl * 64 + ((gk ^ (nl & 7)) * 8));
            }
            #pragma unroll
            for (int rt = 0; rt < 4; ++rt)
                #pragma unroll
                for (int ct = 0; ct < 4; ++ct)
                    acc[rt][ct] = __builtin_amdgcn_mfma_f32_16x16x32_bf16(
                        a[rt], bb[ct], acc[rt][ct], 0, 0, 0);
        }
        __syncthreads();
    }

    const int m  = n0 >> 10;                 // uniform per block
    const int h  = ((n0 >> 6) + wc) & 15;    // one head per wave
    const int bb_ = r0 >> 9;                 // batch
    const int s0 = (r0 & 511) + wr * 64;

    if (m == 2) {
        unsigned short* outv = qkvb + ((size_t)(2 * BH) + (bb_ * H + h)) * (size_t)(S * DH);
        #pragma unroll
        for (int rt = 0; rt < 4; ++rt) {
            int srow = s0 + rt * 16 + quad * 4;
            #pragma unroll
            for (int ct = 0; ct < 4; ++ct) {
                int e = ct * 16 + lane15;
                ushort4 pk;
                pk.x = f2bf(acc[rt][ct][0]);
                pk.y = f2bf(acc[rt][ct][1]);
                pk.z = f2bf(acc[rt][ct][2]);
                pk.w = f2bf(acc[rt][ct][3]);
                *(ushort4*)(outv + (size_t)e * S + srow) = pk;
            }
        }
    } else {
        const float sc = (m == 0) ? 0.04508422002778011f : 1.0f; // (1/32)*log2e
        unsigned short* out = qkvb + ((size_t)m * BH + (bb_ * H + h)) * (size_t)(S * DH);
        #pragma unroll
        for (int rt = 0; rt < 4; ++rt) {
            #pragma unroll
            for (int ct = 0; ct < 4; ++ct) {
                int e = ct * 16 + lane15;
                #pragma unroll
                for (int r = 0; r < 4; ++r) {
                    int srow = s0 + rt * 16 + quad * 4 + r;
                    out[(size_t)srow * DH + e] = f2bf(acc[rt][ct][r] * sc);
                }
            }
        }
    }
}

// ---------------------------------------------------------------------------
// Flash attention, ZERO-SYNC form: per block = (256 q-rows) x (one bh).
// The block's ENTIRE working set fits LDS exactly:
//   Qs 256x64 (32 KB) + K 8x[64][64] (64 KB) + V^T 8x[64][64] (64 KB) = 160 KB.
// Stage everything once with coalesced global_load_lds (512 thr x 20 loads),
// ONE vmcnt(0)+barrier total, then 8 k-tiles of pure ds_read+MFMA+exp2 —
// no barriers, no waits, no LDS writes after the barrier (compiler gets
// full reorder freedom; 2 waves/SIMD provide TLP).
// This removes both prior failure modes: per-iter vmcnt(0) drains
// (rounds 0-3) and scattered direct-global fragment gathers (round 5).
// S^T trick retained: S^T = K.Q^T with K rows permuted per 64-tile by
//   g(r) = r[5]*32 | r[3:2]*8 | r[4]*4 | r[1:0]
// so exp2'd C-registers pack IN-LANE into the PV B-fragment; fragment
// indexing/swizzle identical to the verified round-3 kernel (tile base
// + tt*4096 is the only change). Grid (S/256, B*H), 8 waves.
// ---------------------------------------------------------------------------
__global__ __launch_bounds__(512) void attn_mfma(
    const unsigned short* __restrict__ qkvb, float* __restrict__ out)
{
    __shared__ unsigned short Qs[256 * 64];        // 32 KB
    __shared__ unsigned short KsA[8 * 64 * 64];    // 64 KB (rows perm by g per tile)
    __shared__ unsigned short VtA[8 * 64 * 64];    // 64 KB (rows = dh per tile)

    const int t = threadIdx.x;
    const int w = t >> 6;                 // 0..7
    const int L = t & 63;
    const int lane15 = L & 15;
    const int quad = L >> 4;
    const int lrow8 = L >> 3;
    const int lg = L & 7;
    const int qr0 = blockIdx.x * 256;
    const int bh = blockIdx.y;
    const int b = bh >> 4, h = bh & 15;

    const unsigned short* qb = qkvb + (size_t)bh * S * DH;
    const unsigned short* kb = qkvb + (size_t)(BH + bh) * S * DH;
    const unsigned short* vt = qkvb + (size_t)(2 * BH + bh) * S * DH; // [64][512]

    // ---- stage Q (4 passes x 8 KB): wave w covers rows i*64 + w*8 .. +7 ----
    #pragma unroll
    for (int i = 0; i < 4; ++i) {
        int base = i * 64 + w * 8;
        int r = base + lrow8;
        int gg = lg ^ (r & 7);
        __builtin_amdgcn_global_load_lds(
            (const __attribute__((address_space(1))) void*)
                (qb + (size_t)(qr0 + r) * DH + gg * 8),
            (__attribute__((address_space(3))) void*)(Qs + base * 64),
            16, 0, 0);
    }
    // ---- stage all 8 K-tiles and 8 V^T-tiles (1 load each per thread) ----
    #pragma unroll
    for (int tt = 0; tt < 8; ++tt) {
        int base = w * 8;
        int r = base + lrow8;                       // row within tile, 0..63
        int gr = (r & 32) | ((r & 12) << 1) | ((r & 16) >> 2) | (r & 3);
        int gg = lg ^ (r & 7);
        __builtin_amdgcn_global_load_lds(
            (const __attribute__((address_space(1))) void*)
                (kb + (size_t)(tt * 64 + gr) * DH + gg * 8),
            (__attribute__((address_space(3))) void*)(KsA + tt * 4096 + base * 64),
            16, 0, 0);
        __builtin_amdgcn_global_load_lds(
            (const __attribute__((address_space(1))) void*)
                (vt + (size_t)r * S + tt * 64 + gg * 8),
            (__attribute__((address_space(3))) void*)(VtA + tt * 4096 + base * 64),
            16, 0, 0);
    }
    VMC0;            // the ONLY wait in the kernel
    BARR;            // the ONLY barrier in the kernel

    // Q fragments: loaded once, live in registers for the whole kernel
    bf16x8 qf[2][2];
    #pragma unroll
    for (int mt = 0; mt < 2; ++mt)
        #pragma unroll
        for (int ks = 0; ks < 2; ++ks) {
            int ml = w * 32 + mt * 16 + lane15;
            int gk = ks * 4 + quad;
            qf[mt][ks] = *(const bf16x8*)(Qs + ml * 64 + ((gk ^ (lane15 & 7)) * 8));
        }

    f32x4 o[2][4] = {};                  // rows = dh-slot, col = qrow(lane15)
    float plsum[2] = {0.f, 0.f};

    #pragma unroll 2
    for (int tt = 0; tt < 8; ++tt) {
        const unsigned short* Kt = KsA + tt * 4096;
        const unsigned short* Vt = VtA + tt * 4096;

        // ---- fragments from LDS (no syncs anywhere in this loop) ----
        bf16x8 kf[2][4], vf[2][4];
        #pragma unroll
        for (int ks = 0; ks < 2; ++ks) {
            int gk = ks * 4 + quad;
            #pragma unroll
            for (int ct = 0; ct < 4; ++ct) {
                int kr = ct * 16 + lane15;   // kr&7 == lane15&7
                kf[ks][ct] = *(const bf16x8*)(Kt + kr * 64 + ((gk ^ (lane15 & 7)) * 8));
                vf[ks][ct] = *(const bf16x8*)(Vt + kr * 64 + ((gk ^ (lane15 & 7)) * 8));
            }
        }

        // ---- S^T = K . Q^T : C row = key-slot (quad*4+reg), col = qrow ----
        f32x4 st[2][4] = {};
        __builtin_amdgcn_s_setprio(1);
        #pragma unroll
        for (int ks = 0; ks < 2; ++ks)
            #pragma unroll
            for (int mt = 0; mt < 2; ++mt)
                #pragma unroll
                for (int ct = 0; ct < 4; ++ct)
                    st[mt][ct] = __builtin_amdgcn_mfma_f32_16x16x32_bf16(
                        kf[ks][ct], qf[mt][ks], st[mt][ct], 0, 0, 0);
        __builtin_amdgcn_s_setprio(0);

        // ---- p = exp2(s); cvt_pk into PV B-fragments; row partials ----
        bf16x8 pB[2][2];
        #pragma unroll
        for (int mt = 0; mt < 2; ++mt) {
            float rs = 0.f;
            union { unsigned u[4]; bf16x8 v; } pu[2];
            #pragma unroll
            for (int ct = 0; ct < 4; ++ct) {
                float p0 = exp2f(st[mt][ct][0]);
                float p1 = exp2f(st[mt][ct][1]);
                float p2 = exp2f(st[mt][ct][2]);
                float p3 = exp2f(st[mt][ct][3]);
                rs += (p0 + p1) + (p2 + p3);
                unsigned lo, hi;
                asm("v_cvt_pk_bf16_f32 %0, %1, %2" : "=v"(lo) : "v"(p0), "v"(p1));
                asm("v_cvt_pk_bf16_f32 %0, %1, %2" : "=v"(hi) : "v"(p2), "v"(p3));
                pu[ct >> 1].u[(ct & 1) * 2 + 0] = lo;
                pu[ct >> 1].u[(ct & 1) * 2 + 1] = hi;
            }
            pB[mt][0] = pu[0].v;
            pB[mt][1] = pu[1].v;
            plsum[mt] += rs;
        }

        // ---- O^T += V^T . P^T  (A = V^T rows, B = in-register P) ----
        __builtin_amdgcn_s_setprio(1);
        #pragma unroll
        for (int ks = 0; ks < 2; ++ks)
            #pragma unroll
            for (int mt = 0; mt < 2; ++mt)
                #pragma unroll
                for (int nt = 0; nt < 4; ++nt)
                    o[mt][nt] = __builtin_amdgcn_mfma_f32_16x16x32_bf16(
                        vf[ks][nt], pB[mt][ks], o[mt][nt], 0, 0, 0);
        __builtin_amdgcn_s_setprio(0);
    }

    // epilogue: quad-reduce row sums, normalize, float4 stores (4 consec dh)
    #pragma unroll
    for (int mt = 0; mt < 2; ++mt) {
        float l = plsum[mt];
        l += __shfl_xor(l, 16, 64);
        l += __shfl_xor(l, 32, 64);
        float inv = 1.0f / l;
        int srow = qr0 + w * 32 + mt * 16 + lane15;
        float* op = out + (size_t)(b * S + srow) * D + h * DH;
        #pragma unroll
        for (int nt = 0; nt < 4; ++nt) {
            float4 v;
            v.x = o[mt][nt][0] * inv;
            v.y = o[mt][nt][1] * inv;
            v.z = o[mt][nt][2] * inv;
            v.w = o[mt][nt][3] * inv;
            *(float4*)(op + nt * 16 + quad * 4) = v;
        }
    }
}

extern "C" void kernel_launch(void* const* d_in, const int* in_sizes, int n_in,
                              void* d_out, int out_size, void* d_ws, size_t ws_size,
                              hipStream_t stream) {
    const float* x  = (const float*)d_in[0];
    const float* Wq = (const float*)d_in[1];
    const float* Wk = (const float*)d_in[2];
    const float* Wv = (const float*)d_in[3];
    float* outp = (float*)d_out;

    // workspace: [0, 50331648) qkvb bf16 (q,k row-major; v transposed)
    //            [50331648, 67108864) xb bf16; [67108864, 73400320) WbT bf16
    unsigned short* qkvb = (unsigned short*)d_ws;
    unsigned short* xb   = (unsigned short*)((char*)d_ws + 50331648);
    unsigned short* WbT  = (unsigned short*)((char*)d_ws + 67108864);

    convert_x<<<dim3((B * S * D / 4) / 256), 256, 0, stream>>>(x, xb);
    convert_w<<<dim3(D / 64, H, 3), 256, 0, stream>>>(Wq, Wk, Wv, WbT);
    qkv_gemm<<<dim3(B * S / 128, 3 * H * DH / 128), 256, 0, stream>>>(xb, WbT, qkvb);
    attn_mfma<<<dim3(S / 256, BH), 512, 0, stream>>>(qkvb, outp);
}

// Round 7
// 192.989 us; speedup vs baseline: 1.1441x; 1.0192x over previous
//
#include <hip/hip_runtime.h>
#include <math.h>

constexpr int B = 16, S = 512, D = 1024, H = 16, DH = 64;
constexpr int BH = B * H;        // 256

typedef short bf16x8 __attribute__((ext_vector_type(8)));
typedef float f32x4  __attribute__((ext_vector_type(4)));

__device__ __forceinline__ unsigned short f2bf(float f) {
    unsigned u = __float_as_uint(f);
    u += 0x7fff + ((u >> 16) & 1);   // RNE
    return (unsigned short)(u >> 16);
}

#define VMC0  asm volatile("s_waitcnt vmcnt(0)" ::: "memory")
#define LGKM0 asm volatile("s_waitcnt lgkmcnt(0)" ::: "memory")
#define BARR  __builtin_amdgcn_s_barrier()

// ---------------------------------------------------------------------------
// MERGED converts (saves one kernel launch; gaps measured >= ~50us total):
//   blocks [0, 8192)    : x fp32 [B*S][D] -> xb bf16
//   blocks [8192, 8960) : W [3][H][D][DH] fp32 -> WbT [3][H][DH][D] bf16
// ---------------------------------------------------------------------------
__global__ __launch_bounds__(256) void convert_all(
    const float* __restrict__ x, unsigned short* __restrict__ xb,
    const float* __restrict__ Wq, const float* __restrict__ Wk,
    const float* __restrict__ Wv, unsigned short* __restrict__ WbT)
{
    __shared__ float tile[64][65];
    const int t = threadIdx.x;
    const int bx = blockIdx.x;

    if (bx < 8192) {
        int i = bx * 256 + t;
        float4 v = ((const float4*)x)[i];
        ushort4 o;
        o.x = f2bf(v.x); o.y = f2bf(v.y); o.z = f2bf(v.z); o.w = f2bf(v.w);
        ((ushort4*)xb)[i] = o;
        return;
    }

    const int cw = bx - 8192;               // 0..767
    const int d0 = (cw & 15) * 64;
    const int h = (cw >> 4) & 15;
    const int m = cw >> 8;                  // 0..2
    const float* W = ((m == 0) ? Wq : (m == 1) ? Wk : Wv) + (size_t)h * D * DH;
    {
        int e = t & 63, dr = t >> 6;
        #pragma unroll
        for (int i = 0; i < 16; ++i) {
            int d = dr * 16 + i;
            tile[d][e] = W[(size_t)(d0 + d) * DH + e];
        }
    }
    __syncthreads();
    {
        int d = t & 63, er = t >> 6;
        unsigned short* out = WbT + (size_t)(m * H + h) * DH * D;
        #pragma unroll
        for (int i = 0; i < 16; ++i) {
            int e = er * 16 + i;
            out[(size_t)e * D + d0 + d] = f2bf(tile[d][e]);
        }
    }
}

// ---------------------------------------------------------------------------
// Fused QKV projection: C[8192][3072] = xb . WbT^T, 128x128 block tile,
// 4 waves in 2x2, each 64x64 (4x4 MFMA 16x16x32 bf16), BK=64, 32 KB LDS.
// ROUND-0 PROVEN FORM (73.7 us, MfmaUtil 28). Do not touch.
// q scaled by (1/sqrt(D))*log2e; v written transposed [bh][DH][S].
// ---------------------------------------------------------------------------
__global__ __launch_bounds__(256) void qkv_gemm(
    const unsigned short* __restrict__ xb,
    const unsigned short* __restrict__ WbT,
    unsigned short* __restrict__ qkvb)
{
    __shared__ unsigned short As[128 * 64];   // 16 KB, swizzled g^(row&7)
    __shared__ unsigned short Bs[128 * 64];   // 16 KB

    const int t = threadIdx.x;
    const int w = t >> 6;
    const int wr = w >> 1, wc = w & 1;
    const int L = t & 63;
    const int lane15 = L & 15;
    const int quad = L >> 4;
    const int lrow8 = L >> 3;
    const int lg = L & 7;

    const int r0 = blockIdx.x * 128;   // global row (b*S+s)
    const int n0 = blockIdx.y * 128;   // global col in [0, 3072)

    f32x4 acc[4][4] = {};

    for (int k0 = 0; k0 < D; k0 += 64) {
        #pragma unroll
        for (int i = 0; i < 4; ++i) {
            int c = w * 4 + i;
            int r = c * 8 + lrow8;
            int gg = lg ^ (r & 7);
            const unsigned short* gp = xb + (size_t)(r0 + r) * D + k0 + gg * 8;
            __builtin_amdgcn_global_load_lds(
                (const __attribute__((address_space(1))) void*)gp,
                (__attribute__((address_space(3))) void*)(As + c * 512),
                16, 0, 0);
            const unsigned short* gq = WbT + (size_t)(n0 + r) * D + k0 + gg * 8;
            __builtin_amdgcn_global_load_lds(
                (const __attribute__((address_space(1))) void*)gq,
                (__attribute__((address_space(3))) void*)(Bs + c * 512),
                16, 0, 0);
        }
        __syncthreads();

        #pragma unroll
        for (int ks = 0; ks < 2; ++ks) {
            int gk = ks * 4 + quad;
            bf16x8 a[4], bb[4];
            #pragma unroll
            for (int rt = 0; rt < 4; ++rt) {
                int ml = wr * 64 + rt * 16 + lane15;
                a[rt] = *(const bf16x8*)(As + ml * 64 + ((gk ^ (ml & 7)) * 8));
            }
            #pragma unroll
            for (int ct = 0; ct < 4; ++ct) {
                int nl = wc * 64 + ct * 16 + lane15;
                bb[ct] = *(const bf16x8*)(Bs + nl * 64 + ((gk ^ (nl & 7)) * 8));
            }
            #pragma unroll
            for (int rt = 0; rt < 4; ++rt)
                #pragma unroll
                for (int ct = 0; ct < 4; ++ct)
                    acc[rt][ct] = __builtin_amdgcn_mfma_f32_16x16x32_bf16(
                        a[rt], bb[ct], acc[rt][ct], 0, 0, 0);
        }
        __syncthreads();
    }

    const int m  = n0 >> 10;                 // uniform per block
    const int h  = ((n0 >> 6) + wc) & 15;    // one head per wave
    const int bb_ = r0 >> 9;                 // batch
    const int s0 = (r0 & 511) + wr * 64;

    if (m == 2) {
        unsigned short* outv = qkvb + ((size_t)(2 * BH) + (bb_ * H + h)) * (size_t)(S * DH);
        #pragma unroll
        for (int rt = 0; rt < 4; ++rt) {
            int srow = s0 + rt * 16 + quad * 4;
            #pragma unroll
            for (int ct = 0; ct < 4; ++ct) {
                int e = ct * 16 + lane15;
                ushort4 pk;
                pk.x = f2bf(acc[rt][ct][0]);
                pk.y = f2bf(acc[rt][ct][1]);
                pk.z = f2bf(acc[rt][ct][2]);
                pk.w = f2bf(acc[rt][ct][3]);
                *(ushort4*)(outv + (size_t)e * S + srow) = pk;
            }
        }
    } else {
        const float sc = (m == 0) ? 0.04508422002778011f : 1.0f; // (1/32)*log2e
        unsigned short* out = qkvb + ((size_t)m * BH + (bb_ * H + h)) * (size_t)(S * DH);
        #pragma unroll
        for (int rt = 0; rt < 4; ++rt) {
            #pragma unroll
            for (int ct = 0; ct < 4; ++ct) {
                int e = ct * 16 + lane15;
                #pragma unroll
                for (int r = 0; r < 4; ++r) {
                    int srow = s0 + rt * 16 + quad * 4 + r;
                    out[(size_t)srow * DH + e] = f2bf(acc[rt][ct][r] * sc);
                }
            }
        }
    }
}

// ---------------------------------------------------------------------------
// Flash attention v7 — OCCUPANCY build. Theory: all prior variants held
// >128 VGPRs -> hard 2 waves/SIMD (m69 quantization), which is why sync
// restructuring never moved the needle (latency chains, no TLP to hide).
// Changes:
//  * 8 waves x 16 q-rows (halves qf/st/o/pB -> peak ~90 VGPR, under the
//    128 cliff); __launch_bounds__(512,4) pins it. -> 16 waves/CU (4/SIMD).
//  * per-use kf/vf loads (K dead before V loads).
//  * Q staged into an overlay of KV[0] (read to regs, barrier, reuse):
//    LDS = 32 KB total -> 2 blocks/CU x 8 waves.
//  * K/V double-buffered; prefetch issued at END of iteration (after all
//    ds_reads — avoids hipcc's forced vmcnt-drain-before-ds_read seen in
//    round 2), drained by the end-of-iter VMC0; exposure hidden by TLP.
// Verified math carried unchanged: S^T = K.Q^T with key permutation
//   g(r) = r[5]*32 | r[3:2]*8 | r[4]*4 | r[1:0],
// in-lane cvt_pk P packing, per-lane row sums + quad reduce.
// Grid (S/128, B*H) = (4, 256), 512 threads.
// ---------------------------------------------------------------------------
__global__ __launch_bounds__(512, 4) void attn_mfma(
    const unsigned short* __restrict__ qkvb, float* __restrict__ out)
{
    __shared__ unsigned short KV[2][2][64 * 64];   // 32 KB; [buf][0]=K, [buf][1]=V^T
    unsigned short* Qs = &KV[0][0][0];             // 16 KB overlay (buf 0)

    const int t = threadIdx.x;
    const int w = t >> 6;          // 0..7
    const int L = t & 63;
    const int lane15 = L & 15;
    const int quad = L >> 4;
    const int lrow8 = L >> 3;
    const int lg = L & 7;
    const int qr0 = blockIdx.x * 128;
    const int bh = blockIdx.y;
    const int b = bh >> 4, h = bh & 15;

    const unsigned short* qb = qkvb + (size_t)bh * S * DH;
    const unsigned short* kb = qkvb + (size_t)(BH + bh) * S * DH;
    const unsigned short* vt = qkvb + (size_t)(2 * BH + bh) * S * DH; // [64][512]

    // ---- stage Q (128 rows, 2 passes x 512 thr x 16B) into overlay ----
    #pragma unroll
    for (int p = 0; p < 2; ++p) {
        int base = p * 64 + w * 8;
        int r = base + lrow8;
        int gg = lg ^ (r & 7);
        __builtin_amdgcn_global_load_lds(
            (const __attribute__((address_space(1))) void*)
                (qb + (size_t)(qr0 + r) * DH + gg * 8),
            (__attribute__((address_space(3))) void*)(Qs + base * 64),
            16, 0, 0);
    }
    VMC0;
    BARR;

    // Q fragments to registers (wave w owns q-rows [qr0+w*16, +16))
    bf16x8 qf[2];
    #pragma unroll
    for (int ks = 0; ks < 2; ++ks) {
        int ml = w * 16 + lane15;
        int gk = ks * 4 + quad;
        qf[ks] = *(const bf16x8*)(Qs + ml * 64 + ((gk ^ (lane15 & 7)) * 8));
    }
    LGKM0;           // Q values in regs before any wave overwrites the overlay
    BARR;

    // ---- stage tile 0 into buf 0 (overwrites overlay; 2 gload_lds/wave) ----
    {
        int r = w * 8 + lrow8;
        int gr = (r & 32) | ((r & 12) << 1) | ((r & 16) >> 2) | (r & 3);
        int gg = lg ^ (r & 7);
        __builtin_amdgcn_global_load_lds(
            (const __attribute__((address_space(1))) void*)
                (kb + (size_t)gr * DH + gg * 8),
            (__attribute__((address_space(3))) void*)(&KV[0][0][0] + (w * 8) * 64),
            16, 0, 0);
        __builtin_amdgcn_global_load_lds(
            (const __attribute__((address_space(1))) void*)
                (vt + (size_t)r * S + gg * 8),
            (__attribute__((address_space(3))) void*)(&KV[0][1][0] + (w * 8) * 64),
            16, 0, 0);
    }
    VMC0;
    BARR;

    f32x4 o[4] = {};                 // rows = dh-slot, col = qrow(lane15)
    float plsum = 0.f;

    #pragma unroll 2
    for (int kt = 0; kt < 8; ++kt) {
        const int cur = kt & 1;
        const unsigned short* Kt  = &KV[cur][0][0];
        const unsigned short* Vtl = &KV[cur][1][0];

        // ---- S^T = K . Q^T (per-use kf loads; kf dead after this) ----
        f32x4 st[4] = {};
        #pragma unroll
        for (int ks = 0; ks < 2; ++ks) {
            int gk = ks * 4 + quad;
            bf16x8 kf[4];
            #pragma unroll
            for (int ct = 0; ct < 4; ++ct) {
                int kr = ct * 16 + lane15;
                kf[ct] = *(const bf16x8*)(Kt + kr * 64 + ((gk ^ (lane15 & 7)) * 8));
            }
            __builtin_amdgcn_s_setprio(1);
            #pragma unroll
            for (int ct = 0; ct < 4; ++ct)
                st[ct] = __builtin_amdgcn_mfma_f32_16x16x32_bf16(
                    kf[ct], qf[ks], st[ct], 0, 0, 0);
            __builtin_amdgcn_s_setprio(0);
        }

        // ---- p = exp2(s); cvt_pk into PV B-fragments; row partials ----
        bf16x8 pB[2];
        {
            float rs = 0.f;
            union { unsigned u[4]; bf16x8 v; } pu[2];
            #pragma unroll
            for (int ct = 0; ct < 4; ++ct) {
                float p0 = exp2f(st[ct][0]);
                float p1 = exp2f(st[ct][1]);
                float p2 = exp2f(st[ct][2]);
                float p3 = exp2f(st[ct][3]);
                rs += (p0 + p1) + (p2 + p3);
                unsigned lo, hi;
                asm("v_cvt_pk_bf16_f32 %0, %1, %2" : "=v"(lo) : "v"(p0), "v"(p1));
                asm("v_cvt_pk_bf16_f32 %0, %1, %2" : "=v"(hi) : "v"(p2), "v"(p3));
                pu[ct >> 1].u[(ct & 1) * 2 + 0] = lo;
                pu[ct >> 1].u[(ct & 1) * 2 + 1] = hi;
            }
            pB[0] = pu[0].v;
            pB[1] = pu[1].v;
            plsum += rs;
        }

        // ---- O^T += V^T . P^T (per-use vf loads) ----
        #pragma unroll
        for (int ks = 0; ks < 2; ++ks) {
            int gk = ks * 4 + quad;
            bf16x8 vf[4];
            #pragma unroll
            for (int nt = 0; nt < 4; ++nt) {
                int dh = nt * 16 + lane15;
                vf[nt] = *(const bf16x8*)(Vtl + dh * 64 + ((gk ^ (lane15 & 7)) * 8));
            }
            __builtin_amdgcn_s_setprio(1);
            #pragma unroll
            for (int nt = 0; nt < 4; ++nt)
                o[nt] = __builtin_amdgcn_mfma_f32_16x16x32_bf16(
                    vf[nt], pB[ks], o[nt], 0, 0, 0);
            __builtin_amdgcn_s_setprio(0);
        }

        // ---- stage next tile into buf cur^1 (after ALL ds_reads of this
        //      iter — no compiler drain-before-read), then drain + barrier.
        //      Write-after-read safe: buf cur^1 last read in iter kt-1,
        //      fenced by that iteration's barrier. ----
        if (kt < 7) {
            int r = w * 8 + lrow8;
            int gr = (r & 32) | ((r & 12) << 1) | ((r & 16) >> 2) | (r & 3);
            int gg = lg ^ (r & 7);
            int kn = (kt + 1) * 64;
            __builtin_amdgcn_global_load_lds(
                (const __attribute__((address_space(1))) void*)
                    (kb + (size_t)(kn + gr) * DH + gg * 8),
                (__attribute__((address_space(3))) void*)(&KV[cur ^ 1][0][0] + (w * 8) * 64),
                16, 0, 0);
            __builtin_amdgcn_global_load_lds(
                (const __attribute__((address_space(1))) void*)
                    (vt + (size_t)r * S + kn + gg * 8),
                (__attribute__((address_space(3))) void*)(&KV[cur ^ 1][1][0] + (w * 8) * 64),
                16, 0, 0);
            VMC0;
            BARR;
        }
    }

    // epilogue: quad-reduce row sums, normalize, float4 stores (4 consec dh)
    {
        float l = plsum;
        l += __shfl_xor(l, 16, 64);
        l += __shfl_xor(l, 32, 64);
        float inv = 1.0f / l;
        int srow = qr0 + w * 16 + lane15;
        float* op = out + (size_t)(b * S + srow) * D + h * DH;
        #pragma unroll
        for (int nt = 0; nt < 4; ++nt) {
            float4 v;
            v.x = o[nt][0] * inv;
            v.y = o[nt][1] * inv;
            v.z = o[nt][2] * inv;
            v.w = o[nt][3] * inv;
            *(float4*)(op + nt * 16 + quad * 4) = v;
        }
    }
}

extern "C" void kernel_launch(void* const* d_in, const int* in_sizes, int n_in,
                              void* d_out, int out_size, void* d_ws, size_t ws_size,
                              hipStream_t stream) {
    const float* x  = (const float*)d_in[0];
    const float* Wq = (const float*)d_in[1];
    const float* Wk = (const float*)d_in[2];
    const float* Wv = (const float*)d_in[3];
    float* outp = (float*)d_out;

    // workspace: [0, 50331648) qkvb bf16 (q,k row-major; v transposed)
    //            [50331648, 67108864) xb bf16; [67108864, 73400320) WbT bf16
    unsigned short* qkvb = (unsigned short*)d_ws;
    unsigned short* xb   = (unsigned short*)((char*)d_ws + 50331648);
    unsigned short* WbT  = (unsigned short*)((char*)d_ws + 67108864);

    convert_all<<<dim3(8192 + 768), 256, 0, stream>>>(x, xb, Wq, Wk, Wv, WbT);
    qkv_gemm<<<dim3(B * S / 128, 3 * H * DH / 128), 256, 0, stream>>>(xb, WbT, qkvb);
    attn_mfma<<<dim3(S / 128, BH), 512, 0, stream>>>(qkvb, outp);
}